// Round 5
// baseline (379.535 us; speedup 1.0000x reference)
//
#include <hip/hip_runtime.h>
#include <hip/hip_bf16.h>

// FeatureAttention: B=4,T=2048,D=2048,H=16,HO=128
// alibi folded into ctx epilogue since softmax rows sum to 1.

#define Tt 2048
#define Dd 2048
#define Mm 8192   // B*T

typedef __attribute__((ext_vector_type(4))) float f32x4;
typedef __attribute__((ext_vector_type(8))) short s16x8;
static_assert(sizeof(s16x8) == 16, "frag size");

typedef const __attribute__((address_space(1))) void* gptr_t;
typedef __attribute__((address_space(3))) void* lptr_t;

__device__ __forceinline__ float bf2f(ushort u) {
    union { unsigned int i; float f; } c; c.i = ((unsigned int)u) << 16; return c.f;
}
__device__ __forceinline__ ushort f2bf(float f) {
    union { float f; unsigned int i; } c; c.f = f;
    return (ushort)((c.i + 0x7FFFu + ((c.i >> 16) & 1u)) >> 16);
}
__device__ __forceinline__ void gload16(const void* g, void* l) {
    __builtin_amdgcn_global_load_lds((gptr_t)g, (lptr_t)l, 16, 0, 0);
}
__device__ __forceinline__ s16x8 ldfrag(const char* p) { return *(const s16x8*)p; }

#define MFMA_BF16(d, a, b) \
    asm("v_mfma_f32_16x16x32_bf16 %0, %1, %2, %0" : "+v"(d) : "v"(a), "v"(b))

// ---------------- conversions ----------------

__global__ __launch_bounds__(256) void convx_kernel(const float* __restrict__ x,
                                                    ushort* __restrict__ xb) {
    const int idx = blockIdx.x * 256 + threadIdx.x;
    const int stride = gridDim.x * 256;
    for (int i = idx; i < Mm * Dd / 4; i += stride) {
        const float4 v = *(const float4*)(x + (size_t)i * 4);
        ushort4 o; o.x = f2bf(v.x); o.y = f2bf(v.y); o.z = f2bf(v.z); o.w = f2bf(v.w);
        *(ushort4*)(xb + (size_t)i * 4) = o;
    }
}

// W [K=d_in][N=d_out] fp32 -> Wt [N][K] bf16
__global__ __launch_bounds__(256) void transw_kernel(const float* __restrict__ W0,
        const float* __restrict__ W1, const float* __restrict__ W2,
        const float* __restrict__ W3, ushort* __restrict__ Wt) {
    __shared__ float tile[64][65];
    const int z = blockIdx.z;
    const float* W = (z == 0) ? W0 : (z == 1) ? W1 : (z == 2) ? W2 : W3;
    ushort* dst = Wt + (size_t)z * ((size_t)Dd * Dd);
    const int n0 = blockIdx.x * 64, k0 = blockIdx.y * 64;
    const int r4 = threadIdx.x >> 6, c = threadIdx.x & 63;
#pragma unroll
    for (int i = 0; i < 16; i++) {
        const int row = i * 4 + r4;
        tile[row][c] = W[(size_t)(k0 + row) * Dd + n0 + c];
    }
    __syncthreads();
#pragma unroll
    for (int i = 0; i < 16; i++) {
        const int row = i * 4 + r4;
        dst[(size_t)(n0 + row) * Dd + k0 + c] = f2bf(tile[c][row]);
    }
}

// ---------------- 256x256 8-phase GEMM: C[M,N] = A[M,K] * Bt[N,K]^T ----------------
// bf16 in, fp32 acc. MODE 0: C bf16 (z-batched over B/C via strides).
// MODE 2: C fp32 + bias.
// 512 threads = 8 waves (2M x 4N), BK=64, 128 KiB LDS double-buffer,
// T2 XOR-swizzle. Phases: in-phase reads (12/4/8/0), NO pre-barrier data
// waits, lgkmcnt(0) after the leading barrier, stages two tiles ahead into
// the CURRENT buffer (B at P2-top, A at P3-top), P3 = stage->MFMA->vmcnt(8)
// ->single barrier (7 barriers/K-tile).

__device__ __forceinline__ void stage_half(char* ldsRegion, const ushort* gRegion,
                                           int ld, int half, int tid) {
#pragma unroll
    for (int j = 0; j < 2; j++) {
        const int Pb = half * 16384 + j * 8192 + (tid >> 6) * 1024;  // wave-uniform
        const int P = Pb + (tid & 63) * 16;                          // lane slot
        const int row = P >> 7;
        const int colb = (P ^ ((row & 7) << 4)) & 127;               // logical col bytes
        gload16(gRegion + (size_t)row * ld + (colb >> 1), ldsRegion + Pb);
    }
}

template <int MODE>
__global__ __launch_bounds__(512, 2) void gemm256_kernel(
        const ushort* __restrict__ A, const ushort* __restrict__ Bt,
        void* __restrict__ Cv, const float* __restrict__ bias,
        int Kdim, int lda, int ldb, int ldc,
        size_t bstride, size_t cstride) {
    extern __shared__ char lds[];   // 2 x (A 32768 + B 32768) = 131072 B

    const int tid = threadIdx.x;
    const int lane = tid & 63;
    const int w = tid >> 6;
    const int wr = w >> 2, wc = w & 3;        // 2 x 4 waves
    const int fr = lane & 15, fq = lane >> 4;

    // XCD-aware bijective swizzle (nwg per z = 256 = 8 XCDs x 32)
    const int bid = blockIdx.x;
    const int wg = (bid & 7) * 32 + (bid >> 3);
    const int m0 = (wg >> 3) * 256;
    const int n0 = (wg & 7) * 256;

    const ushort* Ag = A + (size_t)m0 * lda;
    const ushort* Bg = Bt + (size_t)blockIdx.z * bstride + (size_t)n0 * ldb;
    const int NT = Kdim >> 6;

    // per-thread invariant LDS read offsets (swizzle: row&7 == fr&7)
    const int aoff = wr * 16384 + fr * 128;
    const int boff = wc * 8192 + fr * 128;
    const int xo = (fr & 7) << 4;
    const int cp0 = (fq * 16) ^ xo;           // k-sub 0
    const int cp1 = (64 + fq * 16) ^ xo;      // k-sub 1

    f32x4 acc[8][4];
#pragma unroll
    for (int i = 0; i < 8; i++)
#pragma unroll
        for (int j = 0; j < 4; j++) acc[i][j] = {0.f, 0.f, 0.f, 0.f};

    s16x8 afX[4][2], afY[4][2], bf01[2][2], bf23[2][2];

    // ---- prologue: stage tile 0 -> buf0 and tile 1 -> buf1; wait tile 0 ----
    {
        char* b0 = lds;
        char* b1 = lds + 65536;
        stage_half(b0,         Ag, lda, 0, tid);
        stage_half(b0,         Ag, lda, 1, tid);
        stage_half(b0 + 32768, Bg, ldb, 0, tid);
        stage_half(b0 + 32768, Bg, ldb, 1, tid);
        if (NT > 1) {
            stage_half(b1,         Ag + 64, lda, 0, tid);
            stage_half(b1,         Ag + 64, lda, 1, tid);
            stage_half(b1 + 32768, Bg + 64, ldb, 0, tid);
            stage_half(b1 + 32768, Bg + 64, ldb, 1, tid);
        }
        __builtin_amdgcn_sched_barrier(0);
        if (NT > 1) asm volatile("s_waitcnt vmcnt(8)" ::: "memory");
        else        asm volatile("s_waitcnt vmcnt(0)" ::: "memory");
        __builtin_amdgcn_s_barrier();
    }

    for (int t = 0; t < NT; ++t) {
        char* bufc = lds + (t & 1) * 65536;
        const char* Ab = bufc + aoff;
        const char* Bb = bufc + 32768 + boff;
        const ushort* Ag2 = Ag + (size_t)(t + 2) * 64;
        const ushort* Bg2 = Bg + (size_t)(t + 2) * 64;

        // ===== P0: reads afX(8)+bf01(4); barrier; lgkm0; MFMA Q0 =====
#pragma unroll
        for (int m = 0; m < 4; m++) {
            afX[m][0] = ldfrag(Ab + m * 2048 + cp0);
            afX[m][1] = ldfrag(Ab + m * 2048 + cp1);
        }
#pragma unroll
        for (int n = 0; n < 2; n++) {
            bf01[n][0] = ldfrag(Bb + n * 2048 + cp0);
            bf01[n][1] = ldfrag(Bb + n * 2048 + cp1);
        }
        __builtin_amdgcn_sched_barrier(0);
        __builtin_amdgcn_s_barrier();
        asm volatile("s_waitcnt lgkmcnt(0)" ::: "memory");
        __builtin_amdgcn_sched_barrier(0);
        __builtin_amdgcn_s_setprio(1);
#pragma unroll
        for (int k = 0; k < 2; k++)
#pragma unroll
            for (int m = 0; m < 4; m++)
#pragma unroll
                for (int n = 0; n < 2; n++) MFMA_BF16(acc[m][n], afX[m][k], bf01[n][k]);
        __builtin_amdgcn_s_setprio(0);
        __builtin_amdgcn_s_barrier();

        // ===== P1: reads bf23(4); barrier; lgkm0; MFMA Q1 =====
#pragma unroll
        for (int n = 0; n < 2; n++) {
            bf23[n][0] = ldfrag(Bb + (n + 2) * 2048 + cp0);
            bf23[n][1] = ldfrag(Bb + (n + 2) * 2048 + cp1);
        }
        __builtin_amdgcn_sched_barrier(0);
        __builtin_amdgcn_s_barrier();
        asm volatile("s_waitcnt lgkmcnt(0)" ::: "memory");
        __builtin_amdgcn_sched_barrier(0);
        __builtin_amdgcn_s_setprio(1);
#pragma unroll
        for (int k = 0; k < 2; k++)
#pragma unroll
            for (int m = 0; m < 4; m++)
#pragma unroll
                for (int n = 0; n < 2; n++) MFMA_BF16(acc[m][n + 2], afX[m][k], bf23[n][k]);
        __builtin_amdgcn_s_setprio(0);
        __builtin_amdgcn_s_barrier();

        // ===== P2: stage B(t+2) (B region free after P1); reads afY(8); MFMA Q2 =====
        if (t + 2 < NT) {
            stage_half(bufc + 32768, Bg2, ldb, 0, tid);
            stage_half(bufc + 32768, Bg2, ldb, 1, tid);
        }
#pragma unroll
        for (int m = 0; m < 4; m++) {
            afY[m][0] = ldfrag(Ab + (m + 4) * 2048 + cp0);
            afY[m][1] = ldfrag(Ab + (m + 4) * 2048 + cp1);
        }
        __builtin_amdgcn_sched_barrier(0);
        __builtin_amdgcn_s_barrier();
        asm volatile("s_waitcnt lgkmcnt(0)" ::: "memory");
        __builtin_amdgcn_sched_barrier(0);
        __builtin_amdgcn_s_setprio(1);
#pragma unroll
        for (int k = 0; k < 2; k++)
#pragma unroll
            for (int m = 0; m < 4; m++)
#pragma unroll
                for (int n = 0; n < 2; n++) MFMA_BF16(acc[m + 4][n], afY[m][k], bf01[n][k]);
        __builtin_amdgcn_s_setprio(0);
        __builtin_amdgcn_s_barrier();

        // ===== P3: stage A(t+2) (A region free after P2); MFMA Q3; vmcnt(8); barrier =====
        if (t + 2 < NT) {
            stage_half(bufc, Ag2, lda, 0, tid);
            stage_half(bufc, Ag2, lda, 1, tid);
        }
        __builtin_amdgcn_sched_barrier(0);
        __builtin_amdgcn_s_setprio(1);
#pragma unroll
        for (int k = 0; k < 2; k++)
#pragma unroll
            for (int m = 0; m < 4; m++)
#pragma unroll
                for (int n = 0; n < 2; n++) MFMA_BF16(acc[m + 4][n + 2], afY[m][k], bf23[n][k]);
        __builtin_amdgcn_s_setprio(0);
        __builtin_amdgcn_sched_barrier(0);
        if (t + 2 < NT) asm volatile("s_waitcnt vmcnt(8)" ::: "memory");  // tile t+1 landed
        else            asm volatile("s_waitcnt vmcnt(0)" ::: "memory");
        __builtin_amdgcn_sched_barrier(0);
        __builtin_amdgcn_s_barrier();
    }

    asm volatile("s_nop 7\ns_nop 7\ns_nop 7");  // MFMA->VALU hazard guard

    if (MODE == 2) {
        float* C = (float*)Cv;
#pragma unroll
        for (int mi = 0; mi < 8; mi++)
#pragma unroll
            for (int ni = 0; ni < 4; ni++)
#pragma unroll
                for (int r = 0; r < 4; r++) {
                    const int row = m0 + wr * 128 + mi * 16 + fq * 4 + r;
                    const int col = n0 + wc * 64 + ni * 16 + fr;
                    C[(size_t)row * ldc + col] = acc[mi][ni][r] + bias[col];
                }
    } else {
        ushort* C = (ushort*)Cv + (size_t)blockIdx.z * cstride;
#pragma unroll
        for (int mi = 0; mi < 8; mi++)
#pragma unroll
            for (int ni = 0; ni < 4; ni++)
#pragma unroll
                for (int r = 0; r < 4; r++) {
                    const int row = m0 + wr * 128 + mi * 16 + fq * 4 + r;
                    const int col = n0 + wc * 64 + ni * 16 + fr;
                    C[(size_t)row * ldc + col] = f2bf(acc[mi][ni][r]);
                }
    }
}

// ---------------- 128x128 GEMM (small batched ctx GEMM) ----------------
// MODE 1: batched per (b,h) ctx GEMM, + alibi, C bf16.

template <int MODE>
__global__ __launch_bounds__(256, 2) void gemm_kernel(
        const ushort* __restrict__ A, const ushort* __restrict__ Bt,
        void* __restrict__ Cv, const float* __restrict__ bias,
        int Kdim, int lda, int ldb, int ldc) {
    __shared__ ushort lsA[128 * 32];
    __shared__ ushort lsB[128 * 32];

    const int tid = threadIdx.x;
    const int w = tid >> 6, lane = tid & 63;
    const int m0 = blockIdx.y * 128;
    const int n0 = blockIdx.x * 128;

    const ushort* Ab = A;
    const ushort* Bb = Bt;
    size_t coff = 0;
    if (MODE == 1) {
        const int z = blockIdx.z, b = z >> 4, h = z & 15;
        const size_t ao = (size_t)b * ((size_t)Tt * Dd) + (size_t)h * 128;
        Ab += ao; Bb += (size_t)z * (128 * 128); coff = ao;
    }

    const int sr = lane >> 2;
    const int sc = (lane & 3) * 8;
    const int c0 = w, c1 = w + 4;
    const int rA0 = c0 * 16 + sr, rA1 = c1 * 16 + sr;

    const int fr = lane & 15, fq = lane >> 4;
    const int wr = (w >> 1) * 64, wc = (w & 1) * 64;

    f32x4 acc[4][4];
#pragma unroll
    for (int i = 0; i < 4; i++)
#pragma unroll
        for (int j = 0; j < 4; j++) acc[i][j] = {0.f, 0.f, 0.f, 0.f};

    for (int kt = 0; kt < Kdim; kt += 32) {
        gload16(Ab + (size_t)(m0 + rA0) * lda + kt + sc, lsA + c0 * 512);
        gload16(Ab + (size_t)(m0 + rA1) * lda + kt + sc, lsA + c1 * 512);
        gload16(Bb + (size_t)(n0 + rA0) * ldb + kt + sc, lsB + c0 * 512);
        gload16(Bb + (size_t)(n0 + rA1) * ldb + kt + sc, lsB + c1 * 512);
        __syncthreads();

        s16x8 afrag[4], bfrag[4];
#pragma unroll
        for (int i = 0; i < 4; i++)
            afrag[i] = *(const s16x8*)(lsA + (wr + i * 16 + fr) * 32 + fq * 8);
#pragma unroll
        for (int j = 0; j < 4; j++)
            bfrag[j] = *(const s16x8*)(lsB + (wc + j * 16 + fr) * 32 + fq * 8);
#pragma unroll
        for (int i = 0; i < 4; i++)
#pragma unroll
            for (int j = 0; j < 4; j++)
                MFMA_BF16(acc[i][j], afrag[i], bfrag[j]);
        __syncthreads();
    }

    asm volatile("s_nop 7\ns_nop 7\ns_nop 7");

    {
        ushort* C = (ushort*)Cv + coff;
#pragma unroll
        for (int i = 0; i < 4; i++)
#pragma unroll
            for (int j = 0; j < 4; j++)
#pragma unroll
                for (int r = 0; r < 4; r++) {
                    const int row = m0 + wr + i * 16 + fq * 4 + r;
                    const int col = n0 + wc + j * 16 + fr;
                    float val = acc[i][j][r];
                    if (MODE == 1) val += 1.0f / (float)(Tt - row);  // feature alibi
                    C[(size_t)row * ldc + col] = f2bf(val);
                }
    }
}

// ---------------- scores: part[s][bh][f][g] = sum_{t in split s} q[t,f] k[t,g] ----------------
// split-K = 4 (256 blocks = 1/CU)

__global__ __launch_bounds__(256) void scores_kernel(const ushort* __restrict__ q,
        const ushort* __restrict__ k, float* __restrict__ part) {
    __shared__ float lsQ[32][128];
    __shared__ float lsK[32][128];
    const int tid = threadIdx.x;
    const int s = blockIdx.x, bh = blockIdx.y;
    const int b = bh >> 4, h = bh & 15;
    const size_t base = (size_t)b * ((size_t)Tt * Dd) + (size_t)h * 128;
    const ushort* qb = q + base;
    const ushort* kb = k + base;
    const int ty = tid >> 4, tx = tid & 15;
    const int f0 = ty * 8, g0 = tx * 8;

    float acc[8][8];
#pragma unroll
    for (int i = 0; i < 8; i++)
#pragma unroll
        for (int j = 0; j < 8; j++) acc[i][j] = 0.f;

    for (int ch = 0; ch < 16; ch++) {
        const int t0 = s * 512 + ch * 32;
#pragma unroll
        for (int ii = 0; ii < 4; ii++) {
            const int e = ii * 1024 + tid * 4;
            const int r = e >> 7, cc = e & 127;
            const size_t ga = (size_t)(t0 + r) * Dd + cc;
            const ushort4 v4 = *(const ushort4*)(qb + ga);
            f32x4 qf = {bf2f(v4.x), bf2f(v4.y), bf2f(v4.z), bf2f(v4.w)};
            *(f32x4*)&lsQ[r][cc] = qf;
            const ushort4 w4 = *(const ushort4*)(kb + ga);
            f32x4 kf = {bf2f(w4.x), bf2f(w4.y), bf2f(w4.z), bf2f(w4.w)};
            *(f32x4*)&lsK[r][cc] = kf;
        }
        __syncthreads();
#pragma unroll 4
        for (int tl = 0; tl < 32; tl++) {
            float qv[8], kv[8];
            *(f32x4*)&qv[0] = *(const f32x4*)&lsQ[tl][f0];
            *(f32x4*)&qv[4] = *(const f32x4*)&lsQ[tl][f0 + 4];
            *(f32x4*)&kv[0] = *(const f32x4*)&lsK[tl][g0];
            *(f32x4*)&kv[4] = *(const f32x4*)&lsK[tl][g0 + 4];
#pragma unroll
            for (int i = 0; i < 8; i++)
#pragma unroll
                for (int j = 0; j < 8; j++)
                    acc[i][j] = fmaf(qv[i], kv[j], acc[i][j]);
        }
        __syncthreads();
    }
    float* pb = part + ((size_t)s * 64 + bh) * 16384;
#pragma unroll
    for (int i = 0; i < 8; i++) {
        f32x4 o0 = {acc[i][0], acc[i][1], acc[i][2], acc[i][3]};
        f32x4 o1 = {acc[i][4], acc[i][5], acc[i][6], acc[i][7]};
        *(f32x4*)&pb[(f0 + i) * 128 + g0] = o0;
        *(f32x4*)&pb[(f0 + i) * 128 + g0 + 4] = o1;
    }
}

// ---------------- softmax over g: wts[bh][f][g] bf16 ----------------

__global__ __launch_bounds__(256) void softmax_kernel(const float* __restrict__ part,
                                                      ushort* __restrict__ wts) {
    const int tid = threadIdx.x;
    const int wv = tid >> 6, lane = tid & 63;
    const int row = blockIdx.x * 4 + wv;
    const float* p = part + (size_t)row * 128 + lane * 2;
    float v0 = 0.f, v1 = 0.f;
#pragma unroll
    for (int s = 0; s < 4; s++) {
        const float2 t = *(const float2*)(p + (size_t)s * 1048576);
        v0 += t.x; v1 += t.y;
    }
    const float sc = 0.088388347648318447f;  // 1/sqrt(128)
    v0 *= sc; v1 *= sc;
    float m = fmaxf(v0, v1);
#pragma unroll
    for (int off = 32; off > 0; off >>= 1) m = fmaxf(m, __shfl_xor(m, off));
    const float e0 = __expf(v0 - m), e1 = __expf(v1 - m);
    float smv = e0 + e1;
#pragma unroll
    for (int off = 32; off > 0; off >>= 1) smv += __shfl_xor(smv, off);
    const float inv = 1.0f / smv;
    ushort2 o; o.x = f2bf(e0 * inv); o.y = f2bf(e1 * inv);
    *(ushort2*)(wts + (size_t)row * 128 + lane * 2) = o;
}

// ---------------- launch ----------------

extern "C" void kernel_launch(void* const* d_in, const int* in_sizes, int n_in,
                              void* d_out, int out_size, void* d_ws, size_t ws_size,
                              hipStream_t stream) {
    const float* x  = (const float*)d_in[0];
    const float* Wq = (const float*)d_in[1];
    const float* Wk = (const float*)d_in[2];
    const float* Wv = (const float*)d_in[3];
    const float* Wp = (const float*)d_in[4];
    const float* bp = (const float*)d_in[5];
    float* out = (float*)d_out;
    char* ws = (char*)d_ws;

    ushort* xb   = (ushort*)(ws);
    ushort* Wt   = (ushort*)(ws + (33ull << 20));
    ushort* q    = (ushort*)(ws + (65ull << 20));
    ushort* k    = (ushort*)(ws + (97ull << 20));
    ushort* v    = (ushort*)(ws + (129ull << 20));
    float*  part = (float*) (ws + (161ull << 20));
    ushort* wts  = (ushort*)(ws + (193ull << 20));
    ushort* ctx  = xb;  // xb dead after qkv-GEMM; reuse for ctx

    const size_t WSZ = (size_t)Dd * Dd;          // elements per transposed weight
    const size_t QSTRIDE = (32ull << 20) / 2;    // q->k->v spacing in elements

    static_cast<void>(hipFuncSetAttribute((const void*)gemm256_kernel<0>,
        hipFuncAttributeMaxDynamicSharedMemorySize, 131072));
    static_cast<void>(hipFuncSetAttribute((const void*)gemm256_kernel<2>,
        hipFuncAttributeMaxDynamicSharedMemorySize, 131072));

    convx_kernel<<<2048, 256, 0, stream>>>(x, xb);
    transw_kernel<<<dim3(32, 32, 4), 256, 0, stream>>>(Wq, Wk, Wv, Wp, Wt);

    // q, k, v projections fused into one z=3 dispatch
    gemm256_kernel<0><<<dim3(256, 1, 3), 512, 131072, stream>>>(
        xb, Wt, q, nullptr, 2048, 2048, 2048, 2048, WSZ, QSTRIDE);

    scores_kernel<<<dim3(4, 64), 256, 0, stream>>>(q, k, part);
    softmax_kernel<<<2048, 256, 0, stream>>>(part, wts);

    // ctx[t,f] = sum_g v[t,g] * wts[f,g] + alibi[t], per (b,h)
    gemm_kernel<1><<<dim3(1, 16, 64), 256, 0, stream>>>(v, wts, ctx, nullptr, 128, 2048, 128, 2048);

    // out = ctx @ Wp + bp  (fp32 out)
    gemm256_kernel<2><<<dim3(256, 1, 1), 512, 131072, stream>>>(
        ctx, Wt + 3 * WSZ, out, bp, 2048, 2048, 2048, 2048, 0, 0);
}

// Round 6
// 376.797 us; speedup vs baseline: 1.0073x; 1.0073x over previous
//
#include <hip/hip_runtime.h>
#include <hip/hip_bf16.h>

// FeatureAttention: B=4,T=2048,D=2048,H=16,HO=128
// alibi folded into ctx epilogue since softmax rows sum to 1.

#define Tt 2048
#define Dd 2048
#define Mm 8192   // B*T

typedef __attribute__((ext_vector_type(4))) float f32x4;
typedef __attribute__((ext_vector_type(8))) short s16x8;
static_assert(sizeof(s16x8) == 16, "frag size");

typedef const __attribute__((address_space(1))) void* gptr_t;
typedef __attribute__((address_space(3))) void* lptr_t;

__device__ __forceinline__ float bf2f(ushort u) {
    union { unsigned int i; float f; } c; c.i = ((unsigned int)u) << 16; return c.f;
}
__device__ __forceinline__ ushort f2bf(float f) {
    union { float f; unsigned int i; } c; c.f = f;
    return (ushort)((c.i + 0x7FFFu + ((c.i >> 16) & 1u)) >> 16);
}
__device__ __forceinline__ void gload16(const void* g, void* l) {
    __builtin_amdgcn_global_load_lds((gptr_t)g, (lptr_t)l, 16, 0, 0);
}
__device__ __forceinline__ s16x8 ldfrag(const char* p) { return *(const s16x8*)p; }

#define MFMA_BF16(d, a, b) \
    asm("v_mfma_f32_16x16x32_bf16 %0, %1, %2, %0" : "+v"(d) : "v"(a), "v"(b))

// ---------------- conversions ----------------

__global__ __launch_bounds__(256) void convx_kernel(const float* __restrict__ x,
                                                    ushort* __restrict__ xb) {
    const int idx = blockIdx.x * 256 + threadIdx.x;
    const int stride = gridDim.x * 256;
    for (int i = idx; i < Mm * Dd / 4; i += stride) {
        const float4 v = *(const float4*)(x + (size_t)i * 4);
        ushort4 o; o.x = f2bf(v.x); o.y = f2bf(v.y); o.z = f2bf(v.z); o.w = f2bf(v.w);
        *(ushort4*)(xb + (size_t)i * 4) = o;
    }
}

// W [K=d_in][N=d_out] fp32 -> Wt [N][K] bf16
__global__ __launch_bounds__(256) void transw_kernel(const float* __restrict__ W0,
        const float* __restrict__ W1, const float* __restrict__ W2,
        const float* __restrict__ W3, ushort* __restrict__ Wt) {
    __shared__ float tile[64][65];
    const int z = blockIdx.z;
    const float* W = (z == 0) ? W0 : (z == 1) ? W1 : (z == 2) ? W2 : W3;
    ushort* dst = Wt + (size_t)z * ((size_t)Dd * Dd);
    const int n0 = blockIdx.x * 64, k0 = blockIdx.y * 64;
    const int r4 = threadIdx.x >> 6, c = threadIdx.x & 63;
#pragma unroll
    for (int i = 0; i < 16; i++) {
        const int row = i * 4 + r4;
        tile[row][c] = W[(size_t)(k0 + row) * Dd + n0 + c];
    }
    __syncthreads();
#pragma unroll
    for (int i = 0; i < 16; i++) {
        const int row = i * 4 + r4;
        dst[(size_t)(n0 + row) * Dd + k0 + c] = f2bf(tile[c][row]);
    }
}

// ---------------- 256x256 8-phase GEMM: C[M,N] = A[M,K] * Bt[N,K]^T ----------------
// bf16 in, fp32 acc. MODE 0: C bf16 (z-batched over B/C via strides).
// MODE 2: C fp32 + bias.
// 512 threads = 8 waves (2M x 4N), BK=64, 128 KiB LDS double-buffer,
// T2 XOR-swizzle. 8-phase / 2-K-tile loop; exactly ONE half-tile staged per
// phase (fine ds_read || G-load || MFMA interleave, m196's lever); pre-barrier
// lgkmcnt(8) on 12-read phases; counted vmcnt(4) at P3/P7. NT must be even.

__device__ __forceinline__ void stage_half(char* ldsRegion, const ushort* gRegion,
                                           int ld, int half, int tid) {
#pragma unroll
    for (int j = 0; j < 2; j++) {
        const int Pb = half * 16384 + j * 8192 + (tid >> 6) * 1024;  // wave-uniform
        const int P = Pb + (tid & 63) * 16;                          // lane slot
        const int row = P >> 7;
        const int colb = (P ^ ((row & 7) << 4)) & 127;               // logical col bytes
        gload16(gRegion + (size_t)row * ld + (colb >> 1), ldsRegion + Pb);
    }
}

template <int MODE>
__global__ __launch_bounds__(512, 2) void gemm256_kernel(
        const ushort* __restrict__ A, const ushort* __restrict__ Bt,
        void* __restrict__ Cv, const float* __restrict__ bias,
        int Kdim, int lda, int ldb, int ldc,
        size_t bstride, size_t cstride) {
    extern __shared__ char lds[];   // 2 x (A 32768 + B 32768) = 131072 B

    const int tid = threadIdx.x;
    const int lane = tid & 63;
    const int w = tid >> 6;
    const int wr = w >> 2, wc = w & 3;        // 2 x 4 waves
    const int fr = lane & 15, fq = lane >> 4;

    // XCD-aware bijective swizzle (nwg per z = 256 = 8 XCDs x 32)
    const int bid = blockIdx.x;
    const int wg = (bid & 7) * 32 + (bid >> 3);
    const int m0 = (wg >> 3) * 256;
    const int n0 = (wg & 7) * 256;

    const ushort* Ag = A + (size_t)m0 * lda;
    const ushort* Bg = Bt + (size_t)blockIdx.z * bstride + (size_t)n0 * ldb;
    const int NT = Kdim >> 6;                 // even

    // per-thread invariant LDS read offsets (swizzle: row&7 == fr&7)
    const int aoff = wr * 16384 + fr * 128;
    const int boff = wc * 8192 + fr * 128;
    const int xo = (fr & 7) << 4;
    const int cp0 = (fq * 16) ^ xo;           // k-sub 0
    const int cp1 = (64 + fq * 16) ^ xo;      // k-sub 1

    char* buf0 = lds;            // even tiles
    char* buf1 = lds + 65536;    // odd tiles
    const char* Ab0 = buf0 + aoff;
    const char* Bb0 = buf0 + 32768 + boff;
    const char* Ab1 = buf1 + aoff;
    const char* Bb1 = buf1 + 32768 + boff;

    f32x4 acc[8][4];
#pragma unroll
    for (int i = 0; i < 8; i++)
#pragma unroll
        for (int j = 0; j < 4; j++) acc[i][j] = {0.f, 0.f, 0.f, 0.f};

    s16x8 afX[4][2], afY[4][2], bf01[2][2], bf23[2][2];

    // ---- prologue: stage tiles 0 (buf0) and 1 (buf1); wait tile 0 ----
    {
        stage_half(buf0,         Ag, lda, 0, tid);
        stage_half(buf0,         Ag, lda, 1, tid);
        stage_half(buf0 + 32768, Bg, ldb, 0, tid);
        stage_half(buf0 + 32768, Bg, ldb, 1, tid);
        stage_half(buf1,         Ag + 64, lda, 0, tid);
        stage_half(buf1,         Ag + 64, lda, 1, tid);
        stage_half(buf1 + 32768, Bg + 64, ldb, 0, tid);
        stage_half(buf1 + 32768, Bg + 64, ldb, 1, tid);
        __builtin_amdgcn_sched_barrier(0);
        asm volatile("s_waitcnt vmcnt(8)" ::: "memory");
        __builtin_amdgcn_s_barrier();
    }

    const int NI = NT >> 1;
    for (int j = 0; j < NI; ++j) {
        const int e = 2 * j;
        const bool sAo = (j > 0);             // stage A(e+1) at P0/P1
        const bool sE2 = (e + 2 < NT);        // stage tile e+2 at P2..P5
        const bool sO2 = (e + 3 < NT);        // stage tile e+3 at P6/P7
        const ushort* AgO  = Ag + (size_t)(e + 1) * 64;
        const ushort* AgE2 = Ag + (size_t)(e + 2) * 64;
        const ushort* BgE2 = Bg + (size_t)(e + 2) * 64;
        const ushort* BgO2 = Bg + (size_t)(e + 3) * 64;

        // ===== P0: reads afX(e)+bf01(e) [12]; stage A-lo(e+1); lgkm(8); bar; Q0 =====
#pragma unroll
        for (int m = 0; m < 4; m++) {
            afX[m][0] = ldfrag(Ab0 + m * 2048 + cp0);
            afX[m][1] = ldfrag(Ab0 + m * 2048 + cp1);
        }
#pragma unroll
        for (int n = 0; n < 2; n++) {
            bf01[n][0] = ldfrag(Bb0 + n * 2048 + cp0);
            bf01[n][1] = ldfrag(Bb0 + n * 2048 + cp1);
        }
        if (sAo) stage_half(buf1, AgO, lda, 0, tid);
        __builtin_amdgcn_sched_barrier(0);
        asm volatile("s_waitcnt lgkmcnt(8)" ::: "memory");
        __builtin_amdgcn_s_barrier();
        asm volatile("s_waitcnt lgkmcnt(0)" ::: "memory");
        __builtin_amdgcn_sched_barrier(0);
        __builtin_amdgcn_s_setprio(1);
#pragma unroll
        for (int k = 0; k < 2; k++)
#pragma unroll
            for (int m = 0; m < 4; m++)
#pragma unroll
                for (int n = 0; n < 2; n++) MFMA_BF16(acc[m][n], afX[m][k], bf01[n][k]);
        __builtin_amdgcn_s_setprio(0);
        __builtin_amdgcn_s_barrier();

        // ===== P1: reads bf23(e) [4]; stage A-hi(e+1); bar; Q1 =====
#pragma unroll
        for (int n = 0; n < 2; n++) {
            bf23[n][0] = ldfrag(Bb0 + (n + 2) * 2048 + cp0);
            bf23[n][1] = ldfrag(Bb0 + (n + 2) * 2048 + cp1);
        }
        if (sAo) stage_half(buf1, AgO, lda, 1, tid);
        __builtin_amdgcn_sched_barrier(0);
        __builtin_amdgcn_s_barrier();
        asm volatile("s_waitcnt lgkmcnt(0)" ::: "memory");
        __builtin_amdgcn_sched_barrier(0);
        __builtin_amdgcn_s_setprio(1);
#pragma unroll
        for (int k = 0; k < 2; k++)
#pragma unroll
            for (int m = 0; m < 4; m++)
#pragma unroll
                for (int n = 0; n < 2; n++) MFMA_BF16(acc[m][n + 2], afX[m][k], bf23[n][k]);
        __builtin_amdgcn_s_setprio(0);
        __builtin_amdgcn_s_barrier();

        // ===== P2: reads afY(e) [8]; stage B-lo(e+2) (buf0-B free after P1); Q2 =====
#pragma unroll
        for (int m = 0; m < 4; m++) {
            afY[m][0] = ldfrag(Ab0 + (m + 4) * 2048 + cp0);
            afY[m][1] = ldfrag(Ab0 + (m + 4) * 2048 + cp1);
        }
        if (sE2) stage_half(buf0 + 32768, BgE2, ldb, 0, tid);
        __builtin_amdgcn_sched_barrier(0);
        __builtin_amdgcn_s_barrier();
        asm volatile("s_waitcnt lgkmcnt(0)" ::: "memory");
        __builtin_amdgcn_sched_barrier(0);
        __builtin_amdgcn_s_setprio(1);
#pragma unroll
        for (int k = 0; k < 2; k++)
#pragma unroll
            for (int m = 0; m < 4; m++)
#pragma unroll
                for (int n = 0; n < 2; n++) MFMA_BF16(acc[m + 4][n], afY[m][k], bf01[n][k]);
        __builtin_amdgcn_s_setprio(0);
        __builtin_amdgcn_s_barrier();

        // ===== P3: stage B-hi(e+2); Q3; vmcnt(4): A(e+1) landed for P4 =====
        if (sE2) stage_half(buf0 + 32768, BgE2, ldb, 1, tid);
        __builtin_amdgcn_sched_barrier(0);
        __builtin_amdgcn_s_setprio(1);
#pragma unroll
        for (int k = 0; k < 2; k++)
#pragma unroll
            for (int m = 0; m < 4; m++)
#pragma unroll
                for (int n = 0; n < 2; n++) MFMA_BF16(acc[m + 4][n + 2], afY[m][k], bf23[n][k]);
        __builtin_amdgcn_s_setprio(0);
        __builtin_amdgcn_sched_barrier(0);
        if (sE2) asm volatile("s_waitcnt vmcnt(4)" ::: "memory");
        else     asm volatile("s_waitcnt vmcnt(0)" ::: "memory");
        __builtin_amdgcn_s_barrier();

        // ===== P4: reads afX(o)+bf01(o) [12]; stage A-lo(e+2) (buf0-A free after P2) =====
#pragma unroll
        for (int m = 0; m < 4; m++) {
            afX[m][0] = ldfrag(Ab1 + m * 2048 + cp0);
            afX[m][1] = ldfrag(Ab1 + m * 2048 + cp1);
        }
#pragma unroll
        for (int n = 0; n < 2; n++) {
            bf01[n][0] = ldfrag(Bb1 + n * 2048 + cp0);
            bf01[n][1] = ldfrag(Bb1 + n * 2048 + cp1);
        }
        if (sE2) stage_half(buf0, AgE2, lda, 0, tid);
        __builtin_amdgcn_sched_barrier(0);
        asm volatile("s_waitcnt lgkmcnt(8)" ::: "memory");
        __builtin_amdgcn_s_barrier();
        asm volatile("s_waitcnt lgkmcnt(0)" ::: "memory");
        __builtin_amdgcn_sched_barrier(0);
        __builtin_amdgcn_s_setprio(1);
#pragma unroll
        for (int k = 0; k < 2; k++)
#pragma unroll
            for (int m = 0; m < 4; m++)
#pragma unroll
                for (int n = 0; n < 2; n++) MFMA_BF16(acc[m][n], afX[m][k], bf01[n][k]);
        __builtin_amdgcn_s_setprio(0);
        __builtin_amdgcn_s_barrier();

        // ===== P5: reads bf23(o) [4]; stage A-hi(e+2); Q1 =====
#pragma unroll
        for (int n = 0; n < 2; n++) {
            bf23[n][0] = ldfrag(Bb1 + (n + 2) * 2048 + cp0);
            bf23[n][1] = ldfrag(Bb1 + (n + 2) * 2048 + cp1);
        }
        if (sE2) stage_half(buf0, AgE2, lda, 1, tid);
        __builtin_amdgcn_sched_barrier(0);
        __builtin_amdgcn_s_barrier();
        asm volatile("s_waitcnt lgkmcnt(0)" ::: "memory");
        __builtin_amdgcn_sched_barrier(0);
        __builtin_amdgcn_s_setprio(1);
#pragma unroll
        for (int k = 0; k < 2; k++)
#pragma unroll
            for (int m = 0; m < 4; m++)
#pragma unroll
                for (int n = 0; n < 2; n++) MFMA_BF16(acc[m][n + 2], afX[m][k], bf23[n][k]);
        __builtin_amdgcn_s_setprio(0);
        __builtin_amdgcn_s_barrier();

        // ===== P6: reads afY(o) [8]; stage B-lo(e+3) (buf1-B free after P5); Q2 =====
#pragma unroll
        for (int m = 0; m < 4; m++) {
            afY[m][0] = ldfrag(Ab1 + (m + 4) * 2048 + cp0);
            afY[m][1] = ldfrag(Ab1 + (m + 4) * 2048 + cp1);
        }
        if (sO2) stage_half(buf1 + 32768, BgO2, ldb, 0, tid);
        __builtin_amdgcn_sched_barrier(0);
        __builtin_amdgcn_s_barrier();
        asm volatile("s_waitcnt lgkmcnt(0)" ::: "memory");
        __builtin_amdgcn_sched_barrier(0);
        __builtin_amdgcn_s_setprio(1);
#pragma unroll
        for (int k = 0; k < 2; k++)
#pragma unroll
            for (int m = 0; m < 4; m++)
#pragma unroll
                for (int n = 0; n < 2; n++) MFMA_BF16(acc[m + 4][n], afY[m][k], bf01[n][k]);
        __builtin_amdgcn_s_setprio(0);
        __builtin_amdgcn_s_barrier();

        // ===== P7: stage B-hi(e+3); Q3; vmcnt(4): tile e+2 landed for next P0 =====
        if (sO2) stage_half(buf1 + 32768, BgO2, ldb, 1, tid);
        __builtin_amdgcn_sched_barrier(0);
        __builtin_amdgcn_s_setprio(1);
#pragma unroll
        for (int k = 0; k < 2; k++)
#pragma unroll
            for (int m = 0; m < 4; m++)
#pragma unroll
                for (int n = 0; n < 2; n++) MFMA_BF16(acc[m + 4][n + 2], afY[m][k], bf23[n][k]);
        __builtin_amdgcn_s_setprio(0);
        __builtin_amdgcn_sched_barrier(0);
        if (sO2) asm volatile("s_waitcnt vmcnt(4)" ::: "memory");
        else     asm volatile("s_waitcnt vmcnt(0)" ::: "memory");
        __builtin_amdgcn_s_barrier();
    }

    asm volatile("s_nop 7\ns_nop 7\ns_nop 7");  // MFMA->VALU hazard guard

    if (MODE == 2) {
        float* C = (float*)Cv;
#pragma unroll
        for (int mi = 0; mi < 8; mi++)
#pragma unroll
            for (int ni = 0; ni < 4; ni++)
#pragma unroll
                for (int r = 0; r < 4; r++) {
                    const int row = m0 + wr * 128 + mi * 16 + fq * 4 + r;
                    const int col = n0 + wc * 64 + ni * 16 + fr;
                    C[(size_t)row * ldc + col] = acc[mi][ni][r] + bias[col];
                }
    } else {
        ushort* C = (ushort*)Cv + (size_t)blockIdx.z * cstride;
#pragma unroll
        for (int mi = 0; mi < 8; mi++)
#pragma unroll
            for (int ni = 0; ni < 4; ni++)
#pragma unroll
                for (int r = 0; r < 4; r++) {
                    const int row = m0 + wr * 128 + mi * 16 + fq * 4 + r;
                    const int col = n0 + wc * 64 + ni * 16 + fr;
                    C[(size_t)row * ldc + col] = f2bf(acc[mi][ni][r]);
                }
    }
}

// ---------------- 128x128 GEMM (small batched ctx GEMM) ----------------
// MODE 1: batched per (b,h) ctx GEMM, + alibi, C bf16.

template <int MODE>
__global__ __launch_bounds__(256, 2) void gemm_kernel(
        const ushort* __restrict__ A, const ushort* __restrict__ Bt,
        void* __restrict__ Cv, const float* __restrict__ bias,
        int Kdim, int lda, int ldb, int ldc) {
    __shared__ ushort lsA[128 * 32];
    __shared__ ushort lsB[128 * 32];

    const int tid = threadIdx.x;
    const int w = tid >> 6, lane = tid & 63;
    const int m0 = blockIdx.y * 128;
    const int n0 = blockIdx.x * 128;

    const ushort* Ab = A;
    const ushort* Bb = Bt;
    size_t coff = 0;
    if (MODE == 1) {
        const int z = blockIdx.z, b = z >> 4, h = z & 15;
        const size_t ao = (size_t)b * ((size_t)Tt * Dd) + (size_t)h * 128;
        Ab += ao; Bb += (size_t)z * (128 * 128); coff = ao;
    }

    const int sr = lane >> 2;
    const int sc = (lane & 3) * 8;
    const int c0 = w, c1 = w + 4;
    const int rA0 = c0 * 16 + sr, rA1 = c1 * 16 + sr;

    const int fr = lane & 15, fq = lane >> 4;
    const int wr = (w >> 1) * 64, wc = (w & 1) * 64;

    f32x4 acc[4][4];
#pragma unroll
    for (int i = 0; i < 4; i++)
#pragma unroll
        for (int j = 0; j < 4; j++) acc[i][j] = {0.f, 0.f, 0.f, 0.f};

    for (int kt = 0; kt < Kdim; kt += 32) {
        gload16(Ab + (size_t)(m0 + rA0) * lda + kt + sc, lsA + c0 * 512);
        gload16(Ab + (size_t)(m0 + rA1) * lda + kt + sc, lsA + c1 * 512);
        gload16(Bb + (size_t)(n0 + rA0) * ldb + kt + sc, lsB + c0 * 512);
        gload16(Bb + (size_t)(n0 + rA1) * ldb + kt + sc, lsB + c1 * 512);
        __syncthreads();

        s16x8 afrag[4], bfrag[4];
#pragma unroll
        for (int i = 0; i < 4; i++)
            afrag[i] = *(const s16x8*)(lsA + (wr + i * 16 + fr) * 32 + fq * 8);
#pragma unroll
        for (int j = 0; j < 4; j++)
            bfrag[j] = *(const s16x8*)(lsB + (wc + j * 16 + fr) * 32 + fq * 8);
#pragma unroll
        for (int i = 0; i < 4; i++)
#pragma unroll
            for (int j = 0; j < 4; j++)
                MFMA_BF16(acc[i][j], afrag[i], bfrag[j]);
        __syncthreads();
    }

    asm volatile("s_nop 7\ns_nop 7\ns_nop 7");

    {
        ushort* C = (ushort*)Cv + coff;
#pragma unroll
        for (int i = 0; i < 4; i++)
#pragma unroll
            for (int j = 0; j < 4; j++)
#pragma unroll
                for (int r = 0; r < 4; r++) {
                    const int row = m0 + wr + i * 16 + fq * 4 + r;
                    const int col = n0 + wc + j * 16 + fr;
                    float val = acc[i][j][r];
                    if (MODE == 1) val += 1.0f / (float)(Tt - row);  // feature alibi
                    C[(size_t)row * ldc + col] = f2bf(val);
                }
    }
}

// ---------------- scores: part[s][bh][f][g] = sum_{t in split s} q[t,f] k[t,g] ----------------
// split-K = 4 (256 blocks = 1/CU)

__global__ __launch_bounds__(256) void scores_kernel(const ushort* __restrict__ q,
        const ushort* __restrict__ k, float* __restrict__ part) {
    __shared__ float lsQ[32][128];
    __shared__ float lsK[32][128];
    const int tid = threadIdx.x;
    const int s = blockIdx.x, bh = blockIdx.y;
    const int b = bh >> 4, h = bh & 15;
    const size_t base = (size_t)b * ((size_t)Tt * Dd) + (size_t)h * 128;
    const ushort* qb = q + base;
    const ushort* kb = k + base;
    const int ty = tid >> 4, tx = tid & 15;
    const int f0 = ty * 8, g0 = tx * 8;

    float acc[8][8];
#pragma unroll
    for (int i = 0; i < 8; i++)
#pragma unroll
        for (int j = 0; j < 8; j++) acc[i][j] = 0.f;

    for (int ch = 0; ch < 16; ch++) {
        const int t0 = s * 512 + ch * 32;
#pragma unroll
        for (int ii = 0; ii < 4; ii++) {
            const int e = ii * 1024 + tid * 4;
            const int r = e >> 7, cc = e & 127;
            const size_t ga = (size_t)(t0 + r) * Dd + cc;
            const ushort4 v4 = *(const ushort4*)(qb + ga);
            f32x4 qf = {bf2f(v4.x), bf2f(v4.y), bf2f(v4.z), bf2f(v4.w)};
            *(f32x4*)&lsQ[r][cc] = qf;
            const ushort4 w4 = *(const ushort4*)(kb + ga);
            f32x4 kf = {bf2f(w4.x), bf2f(w4.y), bf2f(w4.z), bf2f(w4.w)};
            *(f32x4*)&lsK[r][cc] = kf;
        }
        __syncthreads();
#pragma unroll 4
        for (int tl = 0; tl < 32; tl++) {
            float qv[8], kv[8];
            *(f32x4*)&qv[0] = *(const f32x4*)&lsQ[tl][f0];
            *(f32x4*)&qv[4] = *(const f32x4*)&lsQ[tl][f0 + 4];
            *(f32x4*)&kv[0] = *(const f32x4*)&lsK[tl][g0];
            *(f32x4*)&kv[4] = *(const f32x4*)&lsK[tl][g0 + 4];
#pragma unroll
            for (int i = 0; i < 8; i++)
#pragma unroll
                for (int j = 0; j < 8; j++)
                    acc[i][j] = fmaf(qv[i], kv[j], acc[i][j]);
        }
        __syncthreads();
    }
    float* pb = part + ((size_t)s * 64 + bh) * 16384;
#pragma unroll
    for (int i = 0; i < 8; i++) {
        f32x4 o0 = {acc[i][0], acc[i][1], acc[i][2], acc[i][3]};
        f32x4 o1 = {acc[i][4], acc[i][5], acc[i][6], acc[i][7]};
        *(f32x4*)&pb[(f0 + i) * 128 + g0] = o0;
        *(f32x4*)&pb[(f0 + i) * 128 + g0 + 4] = o1;
    }
}

// ---------------- softmax over g: wts[bh][f][g] bf16 ----------------

__global__ __launch_bounds__(256) void softmax_kernel(const float* __restrict__ part,
                                                      ushort* __restrict__ wts) {
    const int tid = threadIdx.x;
    const int wv = tid >> 6, lane = tid & 63;
    const int row = blockIdx.x * 4 + wv;
    const float* p = part + (size_t)row * 128 + lane * 2;
    float v0 = 0.f, v1 = 0.f;
#pragma unroll
    for (int s = 0; s < 4; s++) {
        const float2 t = *(const float2*)(p + (size_t)s * 1048576);
        v0 += t.x; v1 += t.y;
    }
    const float sc = 0.088388347648318447f;  // 1/sqrt(128)
    v0 *= sc; v1 *= sc;
    float m = fmaxf(v0, v1);
#pragma unroll
    for (int off = 32; off > 0; off >>= 1) m = fmaxf(m, __shfl_xor(m, off));
    const float e0 = __expf(v0 - m), e1 = __expf(v1 - m);
    float smv = e0 + e1;
#pragma unroll
    for (int off = 32; off > 0; off >>= 1) smv += __shfl_xor(smv, off);
    const float inv = 1.0f / smv;
    ushort2 o; o.x = f2bf(e0 * inv); o.y = f2bf(e1 * inv);
    *(ushort2*)(wts + (size_t)row * 128 + lane * 2) = o;
}

// ---------------- launch ----------------

extern "C" void kernel_launch(void* const* d_in, const int* in_sizes, int n_in,
                              void* d_out, int out_size, void* d_ws, size_t ws_size,
                              hipStream_t stream) {
    const float* x  = (const float*)d_in[0];
    const float* Wq = (const float*)d_in[1];
    const float* Wk = (const float*)d_in[2];
    const float* Wv = (const float*)d_in[3];
    const float* Wp = (const float*)d_in[4];
    const float* bp = (const float*)d_in[5];
    float* out = (float*)d_out;
    char* ws = (char*)d_ws;

    ushort* xb   = (ushort*)(ws);
    ushort* Wt   = (ushort*)(ws + (33ull << 20));
    ushort* q    = (ushort*)(ws + (65ull << 20));
    ushort* k    = (ushort*)(ws + (97ull << 20));
    ushort* v    = (ushort*)(ws + (129ull << 20));
    float*  part = (float*) (ws + (161ull << 20));
    ushort* wts  = (ushort*)(ws + (193ull << 20));
    ushort* ctx  = xb;  // xb dead after qkv-GEMM; reuse for ctx

    const size_t WSZ = (size_t)Dd * Dd;          // elements per transposed weight
    const size_t QSTRIDE = (32ull << 20) / 2;    // q->k->v spacing in elements

    static_cast<void>(hipFuncSetAttribute((const void*)gemm256_kernel<0>,
        hipFuncAttributeMaxDynamicSharedMemorySize, 131072));
    static_cast<void>(hipFuncSetAttribute((const void*)gemm256_kernel<2>,
        hipFuncAttributeMaxDynamicSharedMemorySize, 131072));

    convx_kernel<<<2048, 256, 0, stream>>>(x, xb);
    transw_kernel<<<dim3(32, 32, 4), 256, 0, stream>>>(Wq, Wk, Wv, Wp, Wt);

    // q, k, v projections fused into one z=3 dispatch
    gemm256_kernel<0><<<dim3(256, 1, 3), 512, 131072, stream>>>(
        xb, Wt, q, nullptr, 2048, 2048, 2048, 2048, WSZ, QSTRIDE);

    scores_kernel<<<dim3(4, 64), 256, 0, stream>>>(q, k, part);
    softmax_kernel<<<2048, 256, 0, stream>>>(part, wts);

    // ctx[t,f] = sum_g v[t,g] * wts[f,g] + alibi[t], per (b,h)
    gemm_kernel<1><<<dim3(1, 16, 64), 256, 0, stream>>>(v, wts, ctx, nullptr, 128, 2048, 128, 2048);

    // out = ctx @ Wp + bp  (fp32 out)
    gemm256_kernel<2><<<dim3(256, 1, 1), 512, 131072, stream>>>(
        ctx, Wt + 3 * WSZ, out, bp, 2048, 2048, 2048, 2048, 0, 0);
}

// Round 7
// 337.318 us; speedup vs baseline: 1.1252x; 1.1170x over previous
//
#include <hip/hip_runtime.h>
#include <hip/hip_bf16.h>

// FeatureAttention: B=4,T=2048,D=2048,H=16,HO=128
// Gram-path: scores_h = Wq_h^T (X^T X) Wk_h  (q,k never materialized).
// alibi folded into ctx epilogue since softmax rows sum to 1.

#define Tt 2048
#define Dd 2048
#define Mm 8192   // B*T

typedef __attribute__((ext_vector_type(4))) float f32x4;
typedef __attribute__((ext_vector_type(8))) short s16x8;
static_assert(sizeof(s16x8) == 16, "frag size");

typedef const __attribute__((address_space(1))) void* gptr_t;
typedef __attribute__((address_space(3))) void* lptr_t;

__device__ __forceinline__ float bf2f(ushort u) {
    union { unsigned int i; float f; } c; c.i = ((unsigned int)u) << 16; return c.f;
}
__device__ __forceinline__ ushort f2bf(float f) {
    union { float f; unsigned int i; } c; c.f = f;
    return (ushort)((c.i + 0x7FFFu + ((c.i >> 16) & 1u)) >> 16);
}
__device__ __forceinline__ void gload16(const void* g, void* l) {
    __builtin_amdgcn_global_load_lds((gptr_t)g, (lptr_t)l, 16, 0, 0);
}
__device__ __forceinline__ s16x8 ldfrag(const char* p) { return *(const s16x8*)p; }

#define MFMA_BF16(d, a, b) \
    d = __builtin_amdgcn_mfma_f32_16x16x32_bf16((a), (b), (d), 0, 0, 0)

// ---------------- fused convert + transpose: x -> xb [b*t][d], xT [b][d][t] ----------------

__global__ __launch_bounds__(256) void convxT_kernel(const float* __restrict__ x,
        ushort* __restrict__ xb, ushort* __restrict__ xT) {
    __shared__ float tile[64][65];
    const int b = blockIdx.z;
    const int t0 = blockIdx.y * 64, d0 = blockIdx.x * 64;
    const int r4 = threadIdx.x >> 6, c = threadIdx.x & 63;
#pragma unroll
    for (int i = 0; i < 16; i++) {
        const int row = i * 4 + r4;
        const size_t g = ((size_t)b * Tt + t0 + row) * Dd + d0 + c;
        const float val = x[g];
        xb[g] = f2bf(val);
        tile[row][c] = val;
    }
    __syncthreads();
#pragma unroll
    for (int i = 0; i < 16; i++) {
        const int row = i * 4 + r4;   // d-row
        xT[(size_t)b * ((size_t)Dd * Tt) + (size_t)(d0 + row) * Tt + t0 + c] =
            f2bf(tile[c][row]);
    }
}

// W [K=d_in][N=d_out] fp32 -> Wt [N][K] bf16
__global__ __launch_bounds__(256) void transw_kernel(const float* __restrict__ W0,
        const float* __restrict__ W1, const float* __restrict__ W2,
        const float* __restrict__ W3, ushort* __restrict__ Wt) {
    __shared__ float tile[64][65];
    const int z = blockIdx.z;
    const float* W = (z == 0) ? W0 : (z == 1) ? W1 : (z == 2) ? W2 : W3;
    ushort* dst = Wt + (size_t)z * ((size_t)Dd * Dd);
    const int n0 = blockIdx.x * 64, k0 = blockIdx.y * 64;
    const int r4 = threadIdx.x >> 6, c = threadIdx.x & 63;
#pragma unroll
    for (int i = 0; i < 16; i++) {
        const int row = i * 4 + r4;
        tile[row][c] = W[(size_t)(k0 + row) * Dd + n0 + c];
    }
    __syncthreads();
#pragma unroll
    for (int i = 0; i < 16; i++) {
        const int row = i * 4 + r4;
        dst[(size_t)(n0 + row) * Dd + k0 + c] = f2bf(tile[c][row]);
    }
}

// ---------------- 256x256 8-phase GEMM: C[M,N] = A[M,K] * Bt[N,K]^T ----------------
// bf16 in, fp32 acc. MODE 0: C bf16. MODE 2: C fp32 + bias.
// z-batched via astride/bstride/cstride. Same R6 schedule; MFMA via builtin.

__device__ __forceinline__ void stage_half(char* ldsRegion, const ushort* gRegion,
                                           int ld, int half, int tid) {
#pragma unroll
    for (int j = 0; j < 2; j++) {
        const int Pb = half * 16384 + j * 8192 + (tid >> 6) * 1024;  // wave-uniform
        const int P = Pb + (tid & 63) * 16;                          // lane slot
        const int row = P >> 7;
        const int colb = (P ^ ((row & 7) << 4)) & 127;               // logical col bytes
        gload16(gRegion + (size_t)row * ld + (colb >> 1), ldsRegion + Pb);
    }
}

template <int MODE>
__global__ __launch_bounds__(512, 2) void gemm256_kernel(
        const ushort* __restrict__ A, const ushort* __restrict__ Bt,
        void* __restrict__ Cv, const float* __restrict__ bias,
        int Kdim, int lda, int ldb, int ldc,
        size_t astride, size_t bstride, size_t cstride) {
    extern __shared__ char lds[];   // 2 x (A 32768 + B 32768) = 131072 B

    const int tid = threadIdx.x;
    const int lane = tid & 63;
    const int w = tid >> 6;
    const int wr = w >> 2, wc = w & 3;        // 2 x 4 waves
    const int fr = lane & 15, fq = lane >> 4;

    // XCD-aware bijective swizzle (gridDim.x % 8 == 0)
    const int bid = blockIdx.x;
    const int cpx = (int)gridDim.x >> 3;
    const int wg = (bid & 7) * cpx + (bid >> 3);
    const int m0 = (wg >> 3) * 256;           // 8 n-tiles (N = 2048)
    const int n0 = (wg & 7) * 256;

    const ushort* Ag = A + (size_t)blockIdx.z * astride + (size_t)m0 * lda;
    const ushort* Bg = Bt + (size_t)blockIdx.z * bstride + (size_t)n0 * ldb;
    const int NT = Kdim >> 6;                 // even

    // per-thread invariant LDS read offsets (swizzle: row&7 == fr&7)
    const int aoff = wr * 16384 + fr * 128;
    const int boff = wc * 8192 + fr * 128;
    const int xo = (fr & 7) << 4;
    const int cp0 = (fq * 16) ^ xo;           // k-sub 0
    const int cp1 = (64 + fq * 16) ^ xo;      // k-sub 1

    char* buf0 = lds;            // even tiles
    char* buf1 = lds + 65536;    // odd tiles
    const char* Ab0 = buf0 + aoff;
    const char* Bb0 = buf0 + 32768 + boff;
    const char* Ab1 = buf1 + aoff;
    const char* Bb1 = buf1 + 32768 + boff;

    f32x4 acc[8][4];
#pragma unroll
    for (int i = 0; i < 8; i++)
#pragma unroll
        for (int j = 0; j < 4; j++) acc[i][j] = {0.f, 0.f, 0.f, 0.f};

    s16x8 afX[4][2], afY[4][2], bf01[2][2], bf23[2][2];

    // ---- prologue: stage tiles 0 (buf0) and 1 (buf1); wait tile 0 ----
    {
        stage_half(buf0,         Ag, lda, 0, tid);
        stage_half(buf0,         Ag, lda, 1, tid);
        stage_half(buf0 + 32768, Bg, ldb, 0, tid);
        stage_half(buf0 + 32768, Bg, ldb, 1, tid);
        stage_half(buf1,         Ag + 64, lda, 0, tid);
        stage_half(buf1,         Ag + 64, lda, 1, tid);
        stage_half(buf1 + 32768, Bg + 64, ldb, 0, tid);
        stage_half(buf1 + 32768, Bg + 64, ldb, 1, tid);
        __builtin_amdgcn_sched_barrier(0);
        asm volatile("s_waitcnt vmcnt(8)" ::: "memory");
        __builtin_amdgcn_s_barrier();
    }

    const int NI = NT >> 1;
    for (int j = 0; j < NI; ++j) {
        const int e = 2 * j;
        const bool sAo = (j > 0);             // stage A(e+1) at P0/P1
        const bool sE2 = (e + 2 < NT);        // stage tile e+2 at P2..P5
        const bool sO2 = (e + 3 < NT);        // stage tile e+3 at P6/P7
        const ushort* AgO  = Ag + (size_t)(e + 1) * 64;
        const ushort* AgE2 = Ag + (size_t)(e + 2) * 64;
        const ushort* BgE2 = Bg + (size_t)(e + 2) * 64;
        const ushort* BgO2 = Bg + (size_t)(e + 3) * 64;

        // ===== P0: reads afX(e)+bf01(e) [12]; stage A-lo(e+1); lgkm(8); bar; Q0 =====
#pragma unroll
        for (int m = 0; m < 4; m++) {
            afX[m][0] = ldfrag(Ab0 + m * 2048 + cp0);
            afX[m][1] = ldfrag(Ab0 + m * 2048 + cp1);
        }
#pragma unroll
        for (int n = 0; n < 2; n++) {
            bf01[n][0] = ldfrag(Bb0 + n * 2048 + cp0);
            bf01[n][1] = ldfrag(Bb0 + n * 2048 + cp1);
        }
        if (sAo) stage_half(buf1, AgO, lda, 0, tid);
        __builtin_amdgcn_sched_barrier(0);
        asm volatile("s_waitcnt lgkmcnt(8)" ::: "memory");
        __builtin_amdgcn_s_barrier();
        asm volatile("s_waitcnt lgkmcnt(0)" ::: "memory");
        __builtin_amdgcn_sched_barrier(0);
        __builtin_amdgcn_s_setprio(1);
#pragma unroll
        for (int k = 0; k < 2; k++)
#pragma unroll
            for (int m = 0; m < 4; m++)
#pragma unroll
                for (int n = 0; n < 2; n++) MFMA_BF16(acc[m][n], afX[m][k], bf01[n][k]);
        __builtin_amdgcn_s_setprio(0);
        __builtin_amdgcn_s_barrier();

        // ===== P1: reads bf23(e) [4]; stage A-hi(e+1); bar; Q1 =====
#pragma unroll
        for (int n = 0; n < 2; n++) {
            bf23[n][0] = ldfrag(Bb0 + (n + 2) * 2048 + cp0);
            bf23[n][1] = ldfrag(Bb0 + (n + 2) * 2048 + cp1);
        }
        if (sAo) stage_half(buf1, AgO, lda, 1, tid);
        __builtin_amdgcn_sched_barrier(0);
        __builtin_amdgcn_s_barrier();
        asm volatile("s_waitcnt lgkmcnt(0)" ::: "memory");
        __builtin_amdgcn_sched_barrier(0);
        __builtin_amdgcn_s_setprio(1);
#pragma unroll
        for (int k = 0; k < 2; k++)
#pragma unroll
            for (int m = 0; m < 4; m++)
#pragma unroll
                for (int n = 0; n < 2; n++) MFMA_BF16(acc[m][n + 2], afX[m][k], bf23[n][k]);
        __builtin_amdgcn_s_setprio(0);
        __builtin_amdgcn_s_barrier();

        // ===== P2: reads afY(e) [8]; stage B-lo(e+2); Q2 =====
#pragma unroll
        for (int m = 0; m < 4; m++) {
            afY[m][0] = ldfrag(Ab0 + (m + 4) * 2048 + cp0);
            afY[m][1] = ldfrag(Ab0 + (m + 4) * 2048 + cp1);
        }
        if (sE2) stage_half(buf0 + 32768, BgE2, ldb, 0, tid);
        __builtin_amdgcn_sched_barrier(0);
        __builtin_amdgcn_s_barrier();
        asm volatile("s_waitcnt lgkmcnt(0)" ::: "memory");
        __builtin_amdgcn_sched_barrier(0);
        __builtin_amdgcn_s_setprio(1);
#pragma unroll
        for (int k = 0; k < 2; k++)
#pragma unroll
            for (int m = 0; m < 4; m++)
#pragma unroll
                for (int n = 0; n < 2; n++) MFMA_BF16(acc[m + 4][n], afY[m][k], bf01[n][k]);
        __builtin_amdgcn_s_setprio(0);
        __builtin_amdgcn_s_barrier();

        // ===== P3: stage B-hi(e+2); Q3; vmcnt(4) =====
        if (sE2) stage_half(buf0 + 32768, BgE2, ldb, 1, tid);
        __builtin_amdgcn_sched_barrier(0);
        __builtin_amdgcn_s_setprio(1);
#pragma unroll
        for (int k = 0; k < 2; k++)
#pragma unroll
            for (int m = 0; m < 4; m++)
#pragma unroll
                for (int n = 0; n < 2; n++) MFMA_BF16(acc[m + 4][n + 2], afY[m][k], bf23[n][k]);
        __builtin_amdgcn_s_setprio(0);
        __builtin_amdgcn_sched_barrier(0);
        if (sE2) asm volatile("s_waitcnt vmcnt(4)" ::: "memory");
        else     asm volatile("s_waitcnt vmcnt(0)" ::: "memory");
        __builtin_amdgcn_s_barrier();

        // ===== P4: reads afX(o)+bf01(o) [12]; stage A-lo(e+2) =====
#pragma unroll
        for (int m = 0; m < 4; m++) {
            afX[m][0] = ldfrag(Ab1 + m * 2048 + cp0);
            afX[m][1] = ldfrag(Ab1 + m * 2048 + cp1);
        }
#pragma unroll
        for (int n = 0; n < 2; n++) {
            bf01[n][0] = ldfrag(Bb1 + n * 2048 + cp0);
            bf01[n][1] = ldfrag(Bb1 + n * 2048 + cp1);
        }
        if (sE2) stage_half(buf0, AgE2, lda, 0, tid);
        __builtin_amdgcn_sched_barrier(0);
        asm volatile("s_waitcnt lgkmcnt(8)" ::: "memory");
        __builtin_amdgcn_s_barrier();
        asm volatile("s_waitcnt lgkmcnt(0)" ::: "memory");
        __builtin_amdgcn_sched_barrier(0);
        __builtin_amdgcn_s_setprio(1);
#pragma unroll
        for (int k = 0; k < 2; k++)
#pragma unroll
            for (int m = 0; m < 4; m++)
#pragma unroll
                for (int n = 0; n < 2; n++) MFMA_BF16(acc[m][n], afX[m][k], bf01[n][k]);
        __builtin_amdgcn_s_setprio(0);
        __builtin_amdgcn_s_barrier();

        // ===== P5: reads bf23(o) [4]; stage A-hi(e+2); Q1 =====
#pragma unroll
        for (int n = 0; n < 2; n++) {
            bf23[n][0] = ldfrag(Bb1 + (n + 2) * 2048 + cp0);
            bf23[n][1] = ldfrag(Bb1 + (n + 2) * 2048 + cp1);
        }
        if (sE2) stage_half(buf0, AgE2, lda, 1, tid);
        __builtin_amdgcn_sched_barrier(0);
        __builtin_amdgcn_s_barrier();
        asm volatile("s_waitcnt lgkmcnt(0)" ::: "memory");
        __builtin_amdgcn_sched_barrier(0);
        __builtin_amdgcn_s_setprio(1);
#pragma unroll
        for (int k = 0; k < 2; k++)
#pragma unroll
            for (int m = 0; m < 4; m++)
#pragma unroll
                for (int n = 0; n < 2; n++) MFMA_BF16(acc[m][n + 2], afX[m][k], bf23[n][k]);
        __builtin_amdgcn_s_setprio(0);
        __builtin_amdgcn_s_barrier();

        // ===== P6: reads afY(o) [8]; stage B-lo(e+3); Q2 =====
#pragma unroll
        for (int m = 0; m < 4; m++) {
            afY[m][0] = ldfrag(Ab1 + (m + 4) * 2048 + cp0);
            afY[m][1] = ldfrag(Ab1 + (m + 4) * 2048 + cp1);
        }
        if (sO2) stage_half(buf1 + 32768, BgO2, ldb, 0, tid);
        __builtin_amdgcn_sched_barrier(0);
        __builtin_amdgcn_s_barrier();
        asm volatile("s_waitcnt lgkmcnt(0)" ::: "memory");
        __builtin_amdgcn_sched_barrier(0);
        __builtin_amdgcn_s_setprio(1);
#pragma unroll
        for (int k = 0; k < 2; k++)
#pragma unroll
            for (int m = 0; m < 4; m++)
#pragma unroll
                for (int n = 0; n < 2; n++) MFMA_BF16(acc[m + 4][n], afY[m][k], bf01[n][k]);
        __builtin_amdgcn_s_setprio(0);
        __builtin_amdgcn_s_barrier();

        // ===== P7: stage B-hi(e+3); Q3; vmcnt(4) =====
        if (sO2) stage_half(buf1 + 32768, BgO2, ldb, 1, tid);
        __builtin_amdgcn_sched_barrier(0);
        __builtin_amdgcn_s_setprio(1);
#pragma unroll
        for (int k = 0; k < 2; k++)
#pragma unroll
            for (int m = 0; m < 4; m++)
#pragma unroll
                for (int n = 0; n < 2; n++) MFMA_BF16(acc[m + 4][n + 2], afY[m][k], bf23[n][k]);
        __builtin_amdgcn_s_setprio(0);
        __builtin_amdgcn_sched_barrier(0);
        if (sO2) asm volatile("s_waitcnt vmcnt(4)" ::: "memory");
        else     asm volatile("s_waitcnt vmcnt(0)" ::: "memory");
        __builtin_amdgcn_s_barrier();
    }

    if (MODE == 2) {
        float* C = (float*)Cv;
#pragma unroll
        for (int mi = 0; mi < 8; mi++)
#pragma unroll
            for (int ni = 0; ni < 4; ni++)
#pragma unroll
                for (int r = 0; r < 4; r++) {
                    const int row = m0 + wr * 128 + mi * 16 + fq * 4 + r;
                    const int col = n0 + wc * 64 + ni * 16 + fr;
                    C[(size_t)row * ldc + col] = acc[mi][ni][r] + bias[col];
                }
    } else {
        ushort* C = (ushort*)Cv + (size_t)blockIdx.z * cstride;
#pragma unroll
        for (int mi = 0; mi < 8; mi++)
#pragma unroll
            for (int ni = 0; ni < 4; ni++)
#pragma unroll
                for (int r = 0; r < 4; r++) {
                    const int row = m0 + wr * 128 + mi * 16 + fq * 4 + r;
                    const int col = n0 + wc * 64 + ni * 16 + fr;
                    C[(size_t)row * ldc + col] = f2bf(acc[mi][ni][r]);
                }
    }
}

// ---------------- 128x128 GEMM ----------------
// MODE 1: batched per (b,h) ctx GEMM, + alibi, C bf16.
// MODE 3: scores GEMM, z = s*64 + bh, split-K=4 over d; C fp32 -> part.

template <int MODE>
__global__ __launch_bounds__(256, 2) void gemm_kernel(
        const ushort* __restrict__ A, const ushort* __restrict__ Bt,
        void* __restrict__ Cv, const float* __restrict__ bias,
        int Kdim, int lda, int ldb, int ldc) {
    __shared__ ushort lsA[128 * 32];
    __shared__ ushort lsB[128 * 32];

    const int tid = threadIdx.x;
    const int w = tid >> 6, lane = tid & 63;
    const int m0 = blockIdx.y * 128;
    const int n0 = blockIdx.x * 128;

    const ushort* Ab = A;
    const ushort* Bb = Bt;
    size_t coff = 0;
    if (MODE == 1) {
        const int z = blockIdx.z, b = z >> 4, h = z & 15;
        const size_t ao = (size_t)b * ((size_t)Tt * Dd) + (size_t)h * 128;
        Ab += ao; Bb += (size_t)z * (128 * 128); coff = ao;
    }
    if (MODE == 3) {
        const int z = blockIdx.z, s = z >> 6, bh = z & 63;
        const int b = bh >> 4, h = bh & 15;
        Ab += (size_t)h * 128 * Dd + (size_t)s * 512;
        Bb += (size_t)b * ((size_t)Dd * Dd) + (size_t)h * 128 * Dd + (size_t)s * 512;
        coff = (size_t)s * (64 * 16384) + (size_t)bh * 16384;
    }

    const int sr = lane >> 2;
    const int sc = (lane & 3) * 8;
    const int c0 = w, c1 = w + 4;
    const int rA0 = c0 * 16 + sr, rA1 = c1 * 16 + sr;

    const int fr = lane & 15, fq = lane >> 4;
    const int wr = (w >> 1) * 64, wc = (w & 1) * 64;

    f32x4 acc[4][4];
#pragma unroll
    for (int i = 0; i < 4; i++)
#pragma unroll
        for (int j = 0; j < 4; j++) acc[i][j] = {0.f, 0.f, 0.f, 0.f};

    for (int kt = 0; kt < Kdim; kt += 32) {
        gload16(Ab + (size_t)(m0 + rA0) * lda + kt + sc, lsA + c0 * 512);
        gload16(Ab + (size_t)(m0 + rA1) * lda + kt + sc, lsA + c1 * 512);
        gload16(Bb + (size_t)(n0 + rA0) * ldb + kt + sc, lsB + c0 * 512);
        gload16(Bb + (size_t)(n0 + rA1) * ldb + kt + sc, lsB + c1 * 512);
        __syncthreads();

        s16x8 afrag[4], bfrag[4];
#pragma unroll
        for (int i = 0; i < 4; i++)
            afrag[i] = *(const s16x8*)(lsA + (wr + i * 16 + fr) * 32 + fq * 8);
#pragma unroll
        for (int j = 0; j < 4; j++)
            bfrag[j] = *(const s16x8*)(lsB + (wc + j * 16 + fr) * 32 + fq * 8);
#pragma unroll
        for (int i = 0; i < 4; i++)
#pragma unroll
            for (int j = 0; j < 4; j++)
                MFMA_BF16(acc[i][j], afrag[i], bfrag[j]);
        __syncthreads();
    }

    if (MODE == 3) {
        float* C = (float*)Cv + coff;
#pragma unroll
        for (int i = 0; i < 4; i++)
#pragma unroll
            for (int j = 0; j < 4; j++)
#pragma unroll
                for (int r = 0; r < 4; r++) {
                    const int row = m0 + wr + i * 16 + fq * 4 + r;
                    const int col = n0 + wc + j * 16 + fr;
                    C[(size_t)row * ldc + col] = acc[i][j][r];
                }
    } else {
        ushort* C = (ushort*)Cv + coff;
#pragma unroll
        for (int i = 0; i < 4; i++)
#pragma unroll
            for (int j = 0; j < 4; j++)
#pragma unroll
                for (int r = 0; r < 4; r++) {
                    const int row = m0 + wr + i * 16 + fq * 4 + r;
                    const int col = n0 + wc + j * 16 + fr;
                    float val = acc[i][j][r];
                    if (MODE == 1) val += 1.0f / (float)(Tt - row);  // feature alibi
                    C[(size_t)row * ldc + col] = f2bf(val);
                }
    }
}

// ---------------- softmax over g: wts[bh][f][g] bf16 (reads 4 split-K partials) ----------------

__global__ __launch_bounds__(256) void softmax_kernel(const float* __restrict__ part,
                                                      ushort* __restrict__ wts) {
    const int tid = threadIdx.x;
    const int wv = tid >> 6, lane = tid & 63;
    const int row = blockIdx.x * 4 + wv;
    const float* p = part + (size_t)row * 128 + lane * 2;
    float v0 = 0.f, v1 = 0.f;
#pragma unroll
    for (int s = 0; s < 4; s++) {
        const float2 t = *(const float2*)(p + (size_t)s * 1048576);
        v0 += t.x; v1 += t.y;
    }
    const float sc = 0.088388347648318447f;  // 1/sqrt(128)
    v0 *= sc; v1 *= sc;
    float m = fmaxf(v0, v1);
#pragma unroll
    for (int off = 32; off > 0; off >>= 1) m = fmaxf(m, __shfl_xor(m, off));
    const float e0 = __expf(v0 - m), e1 = __expf(v1 - m);
    float smv = e0 + e1;
#pragma unroll
    for (int off = 32; off > 0; off >>= 1) smv += __shfl_xor(smv, off);
    const float inv = 1.0f / smv;
    ushort2 o; o.x = f2bf(e0 * inv); o.y = f2bf(e1 * inv);
    *(ushort2*)(wts + (size_t)row * 128 + lane * 2) = o;
}

// ---------------- launch ----------------

extern "C" void kernel_launch(void* const* d_in, const int* in_sizes, int n_in,
                              void* d_out, int out_size, void* d_ws, size_t ws_size,
                              hipStream_t stream) {
    const float* x  = (const float*)d_in[0];
    const float* Wq = (const float*)d_in[1];
    const float* Wk = (const float*)d_in[2];
    const float* Wv = (const float*)d_in[3];
    const float* Wp = (const float*)d_in[4];
    const float* bp = (const float*)d_in[5];
    float* out = (float*)d_out;
    char* ws = (char*)d_ws;

    // ws layout (MB): xb 0-32 | xT 32-64 | Wt 64-96 | G 96-128 | H 128-160 | v 160-192
    // overlays: part -> G region (96-112), wts -> 112-114, ctx -> xT region (32-64)
    ushort* xb  = (ushort*)(ws);
    ushort* xT  = (ushort*)(ws + (32ull << 20));
    ushort* Wt  = (ushort*)(ws + (64ull << 20));
    ushort* G   = (ushort*)(ws + (96ull << 20));
    ushort* Hb  = (ushort*)(ws + (128ull << 20));
    ushort* v   = (ushort*)(ws + (160ull << 20));
    float*  part = (float*)(ws + (96ull << 20));   // overlays G (dead after H)
    ushort* wts = (ushort*)(ws + (112ull << 20));
    ushort* ctx = xT;                               // xT dead after G

    const size_t WSZ = (size_t)Dd * Dd;  // 4M elements

    static_cast<void>(hipFuncSetAttribute((const void*)gemm256_kernel<0>,
        hipFuncAttributeMaxDynamicSharedMemorySize, 131072));
    static_cast<void>(hipFuncSetAttribute((const void*)gemm256_kernel<2>,
        hipFuncAttributeMaxDynamicSharedMemorySize, 131072));

    convxT_kernel<<<dim3(32, 32, 4), 256, 0, stream>>>(x, xb, xT);
    transw_kernel<<<dim3(32, 32, 4), 256, 0, stream>>>(Wq, Wk, Wv, Wp, Wt);

    // G_b = X_b^T X_b : A = Bt = xT_b [d][t]
    gemm256_kernel<0><<<dim3(64, 1, 4), 512, 131072, stream>>>(
        xT, xT, G, nullptr, 2048, 2048, 2048, 2048, WSZ, WSZ, WSZ);

    // H_b = Wk^T G_b : A = Wt_k, Bt = G_b  (H[n][e] = (G Wk)[e][n])
    gemm256_kernel<0><<<dim3(64, 1, 4), 512, 131072, stream>>>(
        Wt + WSZ, G, Hb, nullptr, 2048, 2048, 2048, 2048, 0, WSZ, WSZ);

    // v = X Wv
    gemm256_kernel<0><<<dim3(256, 1, 1), 512, 131072, stream>>>(
        xb, Wt + 2 * WSZ, v, nullptr, 2048, 2048, 2048, 2048, 0, 0, 0);

    // scores: part[s][bh][f][g] = sum_{d in slice s} Wt_q[hf][d] * H_b[hg][d]
    gemm_kernel<3><<<dim3(1, 1, 256), 256, 0, stream>>>(
        Wt, Hb, part, nullptr, 512, 2048, 2048, 128);

    softmax_kernel<<<2048, 256, 0, stream>>>(part, wts);

    // ctx[t,f] = sum_g v[t,g] * wts[f,g] + alibi[t], per (b,h)
    gemm_kernel<1><<<dim3(1, 16, 64), 256, 0, stream>>>(
        v, wts, ctx, nullptr, 128, 2048, 128, 2048);

    // out = ctx @ Wp + bp  (fp32 out)
    gemm256_kernel<2><<<dim3(256, 1, 1), 512, 131072, stream>>>(
        ctx, Wt + 3 * WSZ, out, bp, 2048, 2048, 2048, 2048, 0, 0, 0);
}